// Round 8
// baseline (440.576 us; speedup 1.0000x reference)
//
#include <hip/hip_runtime.h>

#define NODES 10000
#define EDGES 160000
#define INF_ 16
#define DD 512
#define GRAPHS 64
#define NOUT 18
#define BN_EPS 1e-5f
#define NBUCK 8

using u16 = unsigned short;
using u32 = unsigned int;
typedef __attribute__((ext_vector_type(8))) _Float16 f16x8;
typedef __attribute__((ext_vector_type(4))) float f32x4;

__device__ __forceinline__ float h2f(u16 u) {
  union { u16 u; _Float16 h; } v; v.u = u; return (float)v.h;
}
__device__ __forceinline__ u16 f2h(float f) {
  union { u16 u; _Float16 h; } v; v.h = (_Float16)f; return v.u;
}
__device__ __forceinline__ void add8(uint4 u, float* a) {
  a[0] += h2f((u16)(u.x & 0xffff)); a[1] += h2f((u16)(u.x >> 16));
  a[2] += h2f((u16)(u.y & 0xffff)); a[3] += h2f((u16)(u.y >> 16));
  a[4] += h2f((u16)(u.z & 0xffff)); a[5] += h2f((u16)(u.z >> 16));
  a[6] += h2f((u16)(u.w & 0xffff)); a[7] += h2f((u16)(u.w >> 16));
}
__device__ __forceinline__ unsigned int pk(float a, float b) {
  return (unsigned int)f2h(a) | ((unsigned int)f2h(b) << 16);
}
__device__ __forceinline__ int lower_bound_dev(const int* __restrict__ batch, int g) {
  int lo = 0, hi = NODES;
  while (lo < hi) { int m = (lo + hi) >> 1; if (batch[m] < g) lo = m + 1; else hi = m; }
  return lo;
}
// Swizzled LDS index (u16 units) for the 32-row A/Mid tile.
// Row stride 1152 B (== 0 mod 128) + XOR of byte-bits 4..6 with row&7:
// MFMA fragment reads (16 lanes x rows 0..15 at one 16B column) spread over
// all 8 16B slots (2 lanes each = free); stage writes stay contiguous-class.
__device__ __forceinline__ int lds_m(int row, int byte) {
  return (row * 1152 + (byte ^ ((row & 7) << 4))) >> 1;
}

// ---- prep: zero bns+gsum + cur, and transpose weights into FRAGMENT-MAJOR fp16 ----
// Wf layout per z-matrix (512 KB): [ntile(32)][kchunk(16)] blocks of 1 KB,
// block = [r16(16)][q(4)][e(8)] fp16 with element = W[kchunk*32+q*8+e][ntile*16+r16].
__global__ __launch_bounds__(256) void k_prep(int* __restrict__ cur, float* __restrict__ bg,
                                              const float* __restrict__ W1b, const float* __restrict__ Wa,
                                              const float* __restrict__ Wb, u16* __restrict__ Wf) {
  __shared__ float tile[32][33];
  int b = blockIdx.x;
  int t = threadIdx.x;
  if (b < 288) {               // zero bns+gsum: 5*NBUCK*1024 + 64*512 = 73728 floats
    bg[b * 256 + t] = 0.f;
    return;
  }
  if (b < 328) {               // zero cur: 10000 ints
    int i = (b - 288) * 256 + t;
    if (i < NODES) cur[i] = 0;
    return;
  }
  int wb = b - 328;            // 0..2303 : 16 nb x 16 kb x 9 z
  int nb = wb & 15, kb = (wb >> 4) & 15, z = wb >> 8;
  const float* src = (z == 0) ? W1b : (z <= 4 ? Wa + (size_t)(z - 1) * DD * DD
                                              : Wb + (size_t)(z - 5) * DD * DD);
  int tx = t & 31, ty = t >> 5;  // 32 x 8
#pragma unroll
  for (int i = 0; i < 4; ++i)
    tile[ty + 8 * i][tx] = src[(size_t)(kb * 32 + ty + 8 * i) * DD + nb * 32 + tx];
  __syncthreads();
  u16* dst = Wf + (size_t)z * 262144;
#pragma unroll
  for (int p = 0; p < 4; ++p) {
    int i = t + 256 * p;               // 0..1023 over the 32x32 tile
    int ntl = i >> 9;                  // 0..1 (two 16-wide n-tiles)
    int rem = i & 511;                 // [r16][q][e]
    int kl = ((rem >> 3) & 3) * 8 + (rem & 7);
    int nl = ntl * 16 + (rem >> 5);
    dst[(size_t)((nb * 2 + ntl) * 16 + kb) * 512 + rem] = f2h(tile[kl][nl]);
  }
}

// ---- CSR build: count -> scan(+reset) -> fill ----
__global__ void k_count(const int* __restrict__ dst, int* __restrict__ cnt) {
  int e = blockIdx.x * 256 + threadIdx.x;
  if (e < EDGES) atomicAdd(&cnt[dst[e]], 1);
}

__global__ __launch_bounds__(1024) void k_scan(int* __restrict__ cnt, int* __restrict__ rowptr) {
  __shared__ int s[1024];
  int t = threadIdx.x;
  int base = t * 10;
  int c[10]; int sum = 0;
#pragma unroll
  for (int i = 0; i < 10; ++i) {
    int idx = base + i;
    c[i] = (idx < NODES) ? cnt[idx] : 0;
    if (idx < NODES) cnt[idx] = 0;
    sum += c[i];
  }
  s[t] = sum; __syncthreads();
  for (int off = 1; off < 1024; off <<= 1) {
    int v = s[t];
    int a = (t >= off) ? s[t - off] : 0;
    __syncthreads();
    s[t] = v + a;
    __syncthreads();
  }
  int run = (t == 0) ? 0 : s[t - 1];
#pragma unroll
  for (int i = 0; i < 10; ++i) { int idx = base + i; if (idx < NODES) rowptr[idx] = run; run += c[i]; }
  if (t == 1023) rowptr[NODES] = s[1023];
}

__global__ void k_fill(const int* __restrict__ src, const int* __restrict__ dst,
                       const int* __restrict__ rowptr, int* __restrict__ cur, int* __restrict__ col) {
  int e = blockIdx.x * 256 + threadIdx.x;
  if (e < EDGES) {
    int d = dst[e];
    int p = atomicAdd(&cur[d], 1);
    col[rowptr[d] + p] = src[e];
  }
}

// ---- one 16x16x32 GEMM pass over the staged 32-row tile (per-wave 32 cols) ----
__device__ __forceinline__ void gemm_tile(const u16* At, const u16* __restrict__ Wz,
                                          int wave, int q, int r16, f32x4 (&acc)[2][2]) {
  const u16* wp = Wz + (size_t)(wave * 2) * 16 * 512 + (r16 * 4 + q) * 8;
#pragma unroll
  for (int ks = 0; ks < 16; ++ks) {
    f16x8 af[2], bh[2];
#pragma unroll
    for (int mt = 0; mt < 2; ++mt)
      af[mt] = *(const f16x8*)(At + lds_m(mt * 16 + r16, ks * 64 + q * 16));
#pragma unroll
    for (int nt = 0; nt < 2; ++nt)
      bh[nt] = *(const f16x8*)(wp + (size_t)(nt * 16 + ks) * 512);
#pragma unroll
    for (int mt = 0; mt < 2; ++mt)
#pragma unroll
      for (int nt = 0; nt < 2; ++nt)
        acc[mt][nt] = __builtin_amdgcn_mfma_f32_16x16x32_f16(af[mt], bh[nt], acc[mt][nt], 0, 0, 0);
  }
}

// ---- shared epilogue: bias + relu + fp16 store + bucketed BN stats ----
__device__ __forceinline__ void gemm_out(f32x4 (&acc)[2][2], const float* __restrict__ bB,
                                         u16* __restrict__ Hout, float* __restrict__ sb,
                                         int M0, int wave, int q, int r16) {
  const int wn = wave * 32;
  float colS[2] = {}, colQ[2] = {};
#pragma unroll
  for (int nt = 0; nt < 2; ++nt) {
    int c = wn + nt * 16 + r16;
    float bv = bB[c];
#pragma unroll
    for (int mt = 0; mt < 2; ++mt) {
#pragma unroll
      for (int rr = 0; rr < 4; ++rr) {
        int row = M0 + mt * 16 + q * 4 + rr;
        if (row < NODES) {
          float v = fmaxf(acc[mt][nt][rr] + bv, 0.f);
          Hout[(size_t)row * DD + c] = f2h(v);
          colS[nt] += v; colQ[nt] += v * v;
        }
      }
    }
  }
#pragma unroll
  for (int nt = 0; nt < 2; ++nt) {
    colS[nt] += __shfl_xor(colS[nt], 16); colS[nt] += __shfl_xor(colS[nt], 32);
    colQ[nt] += __shfl_xor(colQ[nt], 16); colQ[nt] += __shfl_xor(colQ[nt], 32);
  }
  if (q == 0) {
#pragma unroll
    for (int nt = 0; nt < 2; ++nt) {
      int c = wn + nt * 16 + r16;
      atomicAdd(&sb[c], colS[nt]);
      atomicAdd(&sb[512 + c], colQ[nt]);
    }
  }
}

// ---- layer 1 fused (BM=32, grid 313): agg16 + MLP-A (VALU) -> At -> gemmB ----
__global__ __launch_bounds__(1024, 2) void k_l1m(const float* __restrict__ x,
    const int* __restrict__ rowptr, const int* __restrict__ col,
    const float* __restrict__ W1a, const float* __restrict__ b1a,
    const u16* __restrict__ WzB, const float* __restrict__ bB,
    u16* __restrict__ Hout, float* __restrict__ statsOut) {
  __shared__ float T0[32][17];
  __shared__ __align__(16) u16 At[32 * 576];   // 36 KB swizzled
  const int T = threadIdx.x;
  const int M0 = blockIdx.x * 32;
  // agg16: threads 0..511 = (node, ch), serial edge loop (same order as ref)
  if (T < 512) {
    int nl = T >> 4, ch = T & 15;
    int node = M0 + nl;
    float acc = 0.f;
    if (node < NODES) {
      acc = x[(size_t)node * INF_ + ch];
      int r1 = rowptr[node + 1];
      for (int idx = rowptr[node]; idx < r1; ++idx)
        acc += x[(size_t)col[idx] * INF_ + ch];
    }
    T0[nl][ch] = acc;
  }
  __syncthreads();
  // MLP-A: thread = (col, row-half); 16 rows each; write relu fp16 into At
  {
    int c = T & 511;
    int h = T >> 9;                    // 0..1 -> rows [h*16, h*16+16)
    float wreg[16];
#pragma unroll
    for (int k = 0; k < 16; ++k) wreg[k] = W1a[k * DD + c];
    float bv = b1a[c];
    for (int r = h * 16; r < h * 16 + 16; ++r) {
      float s = bv;
#pragma unroll
      for (int k = 0; k < 16; ++k) s = fmaf(T0[r][k], wreg[k], s);
      At[lds_m(r, c * 2)] = f2h(fmaxf(s, 0.f));
    }
  }
  __syncthreads();
  const int lane = T & 63, wave = T >> 6;
  const int q = lane >> 4, r16 = lane & 15;
  f32x4 acc[2][2] = {};
  gemm_tile(At, WzB, wave, q, r16, acc);
  gemm_out(acc, bB, Hout, statsOut + (size_t)(blockIdx.x & (NBUCK - 1)) * 1024,
           M0, wave, q, r16);
}

// ---- fused layer (BM=32, grid 313): BN-finalize -> gather+affine -> gemmA -> Mid -> gemmB ----
// 40 KB LDS -> 2 blocks/CU co-resident (wave-slot-limited); grid covers all CUs.
__global__ __launch_bounds__(1024, 2) void k_fused(
    const u16* __restrict__ Hin, const int* __restrict__ rowptr, const int* __restrict__ col,
    const float* __restrict__ statsIn, const float* __restrict__ gamma, const float* __restrict__ beta,
    const u16* __restrict__ WzA, const float* __restrict__ bA,
    const u16* __restrict__ WzB, const float* __restrict__ bB,
    u16* __restrict__ Hout, float* __restrict__ statsOut) {
  __shared__ float ssc[512], ssh[512];
  __shared__ __align__(16) u16 At[32 * 576];   // 36 KB swizzled; Mid reuses it
  const int T = threadIdx.x;
  const int M0 = blockIdx.x * 32;
  // phase 0: BN finalize from buckets (threads 0..511)
  if (T < 512) {
    int c = T;
    float s = 0.f, qv = 0.f;
#pragma unroll
    for (int b = 0; b < NBUCK; ++b) {
      s += statsIn[b * 1024 + c];
      qv += statsIn[b * 1024 + 512 + c];
    }
    float mean = s * (1.f / NODES);
    float var = qv * (1.f / NODES) - mean * mean;
    float sc = gamma[c] * rsqrtf(var + BN_EPS);
    ssc[c] = sc;
    ssh[c] = beta[c] - mean * sc;
  }
  __syncthreads();
  // phase 1: gather 32 nodes (wave w -> nodes w*2, w*2+1), full-row 16B/lane
  const int lane = T & 63, wave = T >> 6;
  const int c8 = lane * 8;
  const u16* hp = Hin + c8;
  float4 scA = *(const float4*)(ssc + c8), scB = *(const float4*)(ssc + c8 + 4);
  float4 shA = *(const float4*)(ssh + c8), shB = *(const float4*)(ssh + c8 + 4);
#pragma unroll
  for (int ps = 0; ps < 2; ++ps) {
    int nl = wave * 2 + ps;
    int node = M0 + nl;
    if (node < NODES) {
      float acc[8];
      {
        uint4 sv = *(const uint4*)(hp + (size_t)node * DD);
        acc[0] = h2f((u16)(sv.x & 0xffff)); acc[1] = h2f((u16)(sv.x >> 16));
        acc[2] = h2f((u16)(sv.y & 0xffff)); acc[3] = h2f((u16)(sv.y >> 16));
        acc[4] = h2f((u16)(sv.z & 0xffff)); acc[5] = h2f((u16)(sv.z >> 16));
        acc[6] = h2f((u16)(sv.w & 0xffff)); acc[7] = h2f((u16)(sv.w >> 16));
      }
      int r0 = rowptr[node], r1 = rowptr[node + 1];
      int idx = r0;
      for (; idx + 7 < r1; idx += 8) {
        int j0 = col[idx], j1 = col[idx + 1], j2 = col[idx + 2], j3 = col[idx + 3];
        int j4 = col[idx + 4], j5 = col[idx + 5], j6 = col[idx + 6], j7 = col[idx + 7];
        uint4 a = *(const uint4*)(hp + (size_t)j0 * DD);
        uint4 b = *(const uint4*)(hp + (size_t)j1 * DD);
        uint4 c = *(const uint4*)(hp + (size_t)j2 * DD);
        uint4 d = *(const uint4*)(hp + (size_t)j3 * DD);
        uint4 e = *(const uint4*)(hp + (size_t)j4 * DD);
        uint4 f = *(const uint4*)(hp + (size_t)j5 * DD);
        uint4 g = *(const uint4*)(hp + (size_t)j6 * DD);
        uint4 h = *(const uint4*)(hp + (size_t)j7 * DD);
        add8(a, acc); add8(b, acc); add8(c, acc); add8(d, acc);
        add8(e, acc); add8(f, acc); add8(g, acc); add8(h, acc);
      }
      for (; idx + 3 < r1; idx += 4) {
        int j0 = col[idx], j1 = col[idx + 1], j2 = col[idx + 2], j3 = col[idx + 3];
        uint4 a = *(const uint4*)(hp + (size_t)j0 * DD);
        uint4 b = *(const uint4*)(hp + (size_t)j1 * DD);
        uint4 c = *(const uint4*)(hp + (size_t)j2 * DD);
        uint4 d = *(const uint4*)(hp + (size_t)j3 * DD);
        add8(a, acc); add8(b, acc); add8(c, acc); add8(d, acc);
      }
      for (; idx < r1; ++idx) {
        uint4 a = *(const uint4*)(hp + (size_t)col[idx] * DD);
        add8(a, acc);
      }
      float nn = (float)(r1 - r0 + 1);
      uint4 o;
      o.x = pk(scA.x * acc[0] + nn * shA.x, scA.y * acc[1] + nn * shA.y);
      o.y = pk(scA.z * acc[2] + nn * shA.z, scA.w * acc[3] + nn * shA.w);
      o.z = pk(scB.x * acc[4] + nn * shB.x, scB.y * acc[5] + nn * shB.y);
      o.w = pk(scB.z * acc[6] + nn * shB.z, scB.w * acc[7] + nn * shB.w);
      *(uint4*)(At + lds_m(nl, lane * 16)) = o;
    } else {
      *(uint4*)(At + lds_m(nl, lane * 16)) = make_uint4(0u, 0u, 0u, 0u);
    }
  }
  __syncthreads();
  // phase 2: gemmA -> Mid (LDS, reuses At) -> gemmB -> Hout + stats
  const int q = lane >> 4, r16 = lane & 15;
  const int wn = wave * 32;
  {
    f32x4 acc[2][2] = {};
    gemm_tile(At, WzA, wave, q, r16, acc);
    __syncthreads();                 // all reads of At done
#pragma unroll
    for (int nt = 0; nt < 2; ++nt) {
      int c = wn + nt * 16 + r16;
      float bv = bA[c];
#pragma unroll
      for (int mt = 0; mt < 2; ++mt)
#pragma unroll
        for (int rr = 0; rr < 4; ++rr)
          At[lds_m(mt * 16 + q * 4 + rr, c * 2)] = f2h(fmaxf(acc[mt][nt][rr] + bv, 0.f));
    }
    __syncthreads();                 // Mid ready
  }
  f32x4 acc[2][2] = {};
  gemm_tile(At, WzB, wave, q, r16, acc);
  gemm_out(acc, bB, Hout, statsOut + (size_t)(blockIdx.x & (NBUCK - 1)) * 1024,
           M0, wave, q, r16);
}

// ---- pooled partial sums: grid (GRAPHS, 8 slices), per-block binary-search bounds ----
__global__ __launch_bounds__(128) void k_pool_part(const u16* __restrict__ h, const int* __restrict__ batch,
                                                   float* __restrict__ gsum) {
  int g = blockIdx.x;
  int s = blockIdx.y;
  int c4 = threadIdx.x * 4;
  int r0 = lower_bound_dev(batch, g);
  int r1 = lower_bound_dev(batch, g + 1);
  int cnt = r1 - r0;
  int len = (cnt + 7) >> 3;
  int rs = r0 + s * len;
  int re = min(rs + len, r1);
  if (rs >= re) return;
  float4 acc = make_float4(0.f, 0.f, 0.f, 0.f);
  for (int r = rs; r < re; ++r) {
    ushort4 v = *(const ushort4*)(h + (size_t)r * DD + c4);
    acc.x += h2f(v.x); acc.y += h2f(v.y); acc.z += h2f(v.z); acc.w += h2f(v.w);
  }
  atomicAdd(&gsum[g * DD + c4 + 0], acc.x);
  atomicAdd(&gsum[g * DD + c4 + 1], acc.y);
  atomicAdd(&gsum[g * DD + c4 + 2], acc.z);
  atomicAdd(&gsum[g * DD + c4 + 3], acc.w);
}

// ---- head: feats = tanh(bn(mean) @ Wfc + bfc); grid (GRAPHS, 8 col-slices), K split 4-way ----
__global__ __launch_bounds__(256) void k_headf(const float* __restrict__ gsum, const int* __restrict__ batch,
                                               const float* __restrict__ stats,
                                               const float* __restrict__ gamma, const float* __restrict__ beta,
                                               const float* __restrict__ Wfc, const float* __restrict__ bfc,
                                               float* __restrict__ feats) {
  __shared__ float pv[512];
  __shared__ float red[4][64];
  int g = blockIdx.x;
  int t = threadIdx.x;
  int r0 = lower_bound_dev(batch, g);
  int r1 = lower_bound_dev(batch, g + 1);
  float inv = 1.f / fmaxf((float)(r1 - r0), 1.f);
#pragma unroll
  for (int r = 0; r < 2; ++r) {
    int c = t + r * 256;
    float s = 0.f, qv = 0.f;
#pragma unroll
    for (int b = 0; b < NBUCK; ++b) {
      s += stats[b * 1024 + c];
      qv += stats[b * 1024 + 512 + c];
    }
    float mean = s * (1.f / NODES);
    float var = qv * (1.f / NODES) - mean * mean;
    float sc = gamma[c] * rsqrtf(var + BN_EPS);
    float sh = beta[c] - mean * sc;
    pv[c] = gsum[g * DD + c] * inv * sc + sh;
  }
  __syncthreads();
  int colc = blockIdx.y * 64 + (t & 63);
  int kc = t >> 6;                      // 0..3
  float p = 0.f;
  int k0 = kc * 128;
  for (int k = k0; k < k0 + 128; ++k)
    p = fmaf(pv[k], Wfc[k * DD + colc], p);
  red[kc][t & 63] = p;
  __syncthreads();
  if (t < 64) {
    int c = blockIdx.y * 64 + t;
    float v = red[0][t] + red[1][t] + red[2][t] + red[3][t] + bfc[c];
    feats[g * DD + c] = tanhf(v);
  }
}

// ---- logits: grid (GRAPHS, NOUT), 64-lane wave reduction ----
__global__ __launch_bounds__(64) void k_logits2(const float* __restrict__ feats, const float* __restrict__ Wlog,
                                                const float* __restrict__ blog, float* __restrict__ out) {
  int g = blockIdx.x, o = blockIdx.y;
  int lane = threadIdx.x;
  float p = 0.f;
  for (int k = lane; k < DD; k += 64)
    p = fmaf(feats[g * DD + k], Wlog[k * NOUT + o], p);
#pragma unroll
  for (int off = 32; off > 0; off >>= 1)
    p += __shfl_down(p, off);
  if (lane == 0) out[g * NOUT + o] = p + blog[o];
}

extern "C" void kernel_launch(void* const* d_in, const int* in_sizes, int n_in,
                              void* d_out, int out_size, void* d_ws, size_t ws_size,
                              hipStream_t stream) {
  const float* x = (const float*)d_in[0];
  const int* ei = (const int*)d_in[1];
  const int* batch = (const int*)d_in[2];
  const float* W1a = (const float*)d_in[3];
  const float* b1a = (const float*)d_in[4];
  const float* W1b = (const float*)d_in[5];
  const float* b1b = (const float*)d_in[6];
  const float* Wa = (const float*)d_in[7];
  const float* ba = (const float*)d_in[8];
  const float* Wb = (const float*)d_in[9];
  const float* bb = (const float*)d_in[10];
  const float* bng = (const float*)d_in[11];
  const float* bnb = (const float*)d_in[12];
  const float* Wfc = (const float*)d_in[13];
  const float* bfc = (const float*)d_in[14];
  const float* Wlog = (const float*)d_in[15];
  const float* blog = (const float*)d_in[16];
  float* out = (float*)d_out;

  const int* src = ei;
  const int* dstp = ei + EDGES;

  char* w = (char*)d_ws;
  int* rowptr  = (int*)(w);                 // 10001 i32 (pad to 40192)
  int* cur     = (int*)(w + 40192);         // 10000 i32
  int* col     = (int*)(w + 80384);         // 160000 i32 -> ends 720384
  float* bns   = (float*)(w + 720384);      // 5 x NBUCK x 1024 f -> ends 884224
  float* gsum  = (float*)(w + 884224);      // 32768 f (contiguous after bns) -> ends 1015296
  float* feats = (float*)(w + 1015296);     // 32768 f -> ends 1146368
  u16* Wf      = (u16*)(w + 1146368);       // 9 x 512 KB fragment-major -> ends 5864960
  u16* H0      = (u16*)(w + 5864960);       // 10,240,000 B
  u16* H1      = (u16*)(w + 16104960);      // 10,240,000 B -> ends 26,344,960

  k_prep<<<2632, 256, 0, stream>>>(cur, bns, W1b, Wa, Wb, Wf);
  k_count<<<625, 256, 0, stream>>>(dstp, cur);
  k_scan<<<1, 1024, 0, stream>>>(cur, rowptr);
  k_fill<<<625, 256, 0, stream>>>(src, dstp, rowptr, cur, col);

  // layer 1 (one kernel): agg16 + MLP-A + gemmB -> H0 + stats0
  k_l1m<<<313, 1024, 0, stream>>>(x, rowptr, col, W1a, b1a, Wf, b1b, H0, bns);

  // layers 2..5 (one kernel each): bnf + gather + double-gemm, ping-pong H0<->H1
  u16* Hin = H0;
  u16* Ho = H1;
  for (int i = 0; i < 4; ++i) {
    k_fused<<<313, 1024, 0, stream>>>(Hin, rowptr, col, bns + (size_t)i * 8192,
        bng + i * DD, bnb + i * DD,
        Wf + (size_t)(1 + i) * 262144, ba + i * DD,
        Wf + (size_t)(5 + i) * 262144, bb + i * DD,
        Ho, bns + (size_t)(i + 1) * 8192);
    u16* tmp = Hin; Hin = Ho; Ho = tmp;
  }

  k_pool_part<<<dim3(GRAPHS, 8), 128, 0, stream>>>(Hin, batch, gsum);
  k_headf<<<dim3(GRAPHS, 8), 256, 0, stream>>>(gsum, batch, bns + (size_t)4 * 8192,
                                               bng + 4 * DD, bnb + 4 * DD, Wfc, bfc, feats);
  k_logits2<<<dim3(GRAPHS, NOUT), 64, 0, stream>>>(feats, Wlog, blog, out);
}

// Round 9
// 350.178 us; speedup vs baseline: 1.2581x; 1.2581x over previous
//
#include <hip/hip_runtime.h>

#define NODES 10000
#define EDGES 160000
#define INF_ 16
#define DD 512
#define GRAPHS 64
#define NOUT 18
#define BN_EPS 1e-5f
#define NBUCK 8
#define BM 40            // rows per block; 250*40 = 10000 exact (one scheduling wave)
#define BMT 48           // padded LDS tile rows (3 x 16 MFMA tiles)

using u16 = unsigned short;
using u32 = unsigned int;
typedef __attribute__((ext_vector_type(8))) _Float16 f16x8;
typedef __attribute__((ext_vector_type(4))) float f32x4;

__device__ __forceinline__ float h2f(u16 u) {
  union { u16 u; _Float16 h; } v; v.u = u; return (float)v.h;
}
__device__ __forceinline__ u16 f2h(float f) {
  union { u16 u; _Float16 h; } v; v.h = (_Float16)f; return v.u;
}
__device__ __forceinline__ void add8(uint4 u, float* a) {
  a[0] += h2f((u16)(u.x & 0xffff)); a[1] += h2f((u16)(u.x >> 16));
  a[2] += h2f((u16)(u.y & 0xffff)); a[3] += h2f((u16)(u.y >> 16));
  a[4] += h2f((u16)(u.z & 0xffff)); a[5] += h2f((u16)(u.z >> 16));
  a[6] += h2f((u16)(u.w & 0xffff)); a[7] += h2f((u16)(u.w >> 16));
}
__device__ __forceinline__ unsigned int pk(float a, float b) {
  return (unsigned int)f2h(a) | ((unsigned int)f2h(b) << 16);
}
__device__ __forceinline__ int lower_bound_dev(const int* __restrict__ batch, int g) {
  int lo = 0, hi = NODES;
  while (lo < hi) { int m = (lo + hi) >> 1; if (batch[m] < g) lo = m + 1; else hi = m; }
  return lo;
}
// Swizzled LDS index (u16 units) for the 48-row A/Mid tile.
// Row stride 1152 B (== 0 mod 128) + XOR of byte-bits 4..6 with row&7:
// MFMA fragment reads (16 lanes x rows 0..15 at one 16B column) spread over
// all 8 16B slots (2 lanes each = free); stage writes stay contiguous-class.
__device__ __forceinline__ int lds_m(int row, int byte) {
  return (row * 1152 + (byte ^ ((row & 7) << 4))) >> 1;
}

// ---- prep: zero bns+gsum + cur, and transpose weights into FRAGMENT-MAJOR fp16 ----
// Wf layout per z-matrix (512 KB): [ntile(32)][kchunk(16)] blocks of 1 KB,
// block = [r16(16)][q(4)][e(8)] fp16 with element = W[kchunk*32+q*8+e][ntile*16+r16].
__global__ __launch_bounds__(256) void k_prep(int* __restrict__ cur, float* __restrict__ bg,
                                              const float* __restrict__ W1b, const float* __restrict__ Wa,
                                              const float* __restrict__ Wb, u16* __restrict__ Wf) {
  __shared__ float tile[32][33];
  int b = blockIdx.x;
  int t = threadIdx.x;
  if (b < 288) {               // zero bns+gsum: 5*NBUCK*1024 + 64*512 = 73728 floats
    bg[b * 256 + t] = 0.f;
    return;
  }
  if (b < 328) {               // zero cur: 10000 ints
    int i = (b - 288) * 256 + t;
    if (i < NODES) cur[i] = 0;
    return;
  }
  int wb = b - 328;            // 0..2303 : 16 nb x 16 kb x 9 z
  int nb = wb & 15, kb = (wb >> 4) & 15, z = wb >> 8;
  const float* src = (z == 0) ? W1b : (z <= 4 ? Wa + (size_t)(z - 1) * DD * DD
                                              : Wb + (size_t)(z - 5) * DD * DD);
  int tx = t & 31, ty = t >> 5;  // 32 x 8
#pragma unroll
  for (int i = 0; i < 4; ++i)
    tile[ty + 8 * i][tx] = src[(size_t)(kb * 32 + ty + 8 * i) * DD + nb * 32 + tx];
  __syncthreads();
  u16* dst = Wf + (size_t)z * 262144;
#pragma unroll
  for (int p = 0; p < 4; ++p) {
    int i = t + 256 * p;               // 0..1023 over the 32x32 tile
    int ntl = i >> 9;                  // 0..1 (two 16-wide n-tiles)
    int rem = i & 511;                 // [r16][q][e]
    int kl = ((rem >> 3) & 3) * 8 + (rem & 7);
    int nl = ntl * 16 + (rem >> 5);
    dst[(size_t)((nb * 2 + ntl) * 16 + kb) * 512 + rem] = f2h(tile[kl][nl]);
  }
}

// ---- CSR build: count -> scan(+reset) -> fill ----
__global__ void k_count(const int* __restrict__ dst, int* __restrict__ cnt) {
  int e = blockIdx.x * 256 + threadIdx.x;
  if (e < EDGES) atomicAdd(&cnt[dst[e]], 1);
}

__global__ __launch_bounds__(1024) void k_scan(int* __restrict__ cnt, int* __restrict__ rowptr) {
  __shared__ int s[1024];
  int t = threadIdx.x;
  int base = t * 10;
  int c[10]; int sum = 0;
#pragma unroll
  for (int i = 0; i < 10; ++i) {
    int idx = base + i;
    c[i] = (idx < NODES) ? cnt[idx] : 0;
    if (idx < NODES) cnt[idx] = 0;
    sum += c[i];
  }
  s[t] = sum; __syncthreads();
  for (int off = 1; off < 1024; off <<= 1) {
    int v = s[t];
    int a = (t >= off) ? s[t - off] : 0;
    __syncthreads();
    s[t] = v + a;
    __syncthreads();
  }
  int run = (t == 0) ? 0 : s[t - 1];
#pragma unroll
  for (int i = 0; i < 10; ++i) { int idx = base + i; if (idx < NODES) rowptr[idx] = run; run += c[i]; }
  if (t == 1023) rowptr[NODES] = s[1023];
}

__global__ void k_fill(const int* __restrict__ src, const int* __restrict__ dst,
                       const int* __restrict__ rowptr, int* __restrict__ cur, int* __restrict__ col) {
  int e = blockIdx.x * 256 + threadIdx.x;
  if (e < EDGES) {
    int d = dst[e];
    int p = atomicAdd(&cur[d], 1);
    col[rowptr[d] + p] = src[e];
  }
}

// ---- one 16x16x32 GEMM pass over the staged 48-row tile (per-wave 32 cols) ----
__device__ __forceinline__ void gemm_tile(const u16* At, const u16* __restrict__ Wz,
                                          int wave, int q, int r16, f32x4 (&acc)[3][2]) {
  const u16* wp = Wz + (size_t)(wave * 2) * 16 * 512 + (r16 * 4 + q) * 8;
#pragma unroll
  for (int ks = 0; ks < 16; ++ks) {
    f16x8 af[3], bh[2];
#pragma unroll
    for (int mt = 0; mt < 3; ++mt)
      af[mt] = *(const f16x8*)(At + lds_m(mt * 16 + r16, ks * 64 + q * 16));
#pragma unroll
    for (int nt = 0; nt < 2; ++nt)
      bh[nt] = *(const f16x8*)(wp + (size_t)(nt * 16 + ks) * 512);
#pragma unroll
    for (int mt = 0; mt < 3; ++mt)
#pragma unroll
      for (int nt = 0; nt < 2; ++nt)
        acc[mt][nt] = __builtin_amdgcn_mfma_f32_16x16x32_f16(af[mt], bh[nt], acc[mt][nt], 0, 0, 0);
  }
}

// ---- shared epilogue: bias + relu + fp16 store + bucketed BN stats (rows < BM only) ----
__device__ __forceinline__ void gemm_out(f32x4 (&acc)[3][2], const float* __restrict__ bB,
                                         u16* __restrict__ Hout, float* __restrict__ sb,
                                         int M0, int wave, int q, int r16) {
  const int wn = wave * 32;
  float colS[2] = {}, colQ[2] = {};
#pragma unroll
  for (int nt = 0; nt < 2; ++nt) {
    int c = wn + nt * 16 + r16;
    float bv = bB[c];
#pragma unroll
    for (int mt = 0; mt < 3; ++mt) {
#pragma unroll
      for (int rr = 0; rr < 4; ++rr) {
        int lr = mt * 16 + q * 4 + rr;
        int row = M0 + lr;
        if (lr < BM && row < NODES) {
          float v = fmaxf(acc[mt][nt][rr] + bv, 0.f);
          Hout[(size_t)row * DD + c] = f2h(v);
          colS[nt] += v; colQ[nt] += v * v;
        }
      }
    }
  }
#pragma unroll
  for (int nt = 0; nt < 2; ++nt) {
    colS[nt] += __shfl_xor(colS[nt], 16); colS[nt] += __shfl_xor(colS[nt], 32);
    colQ[nt] += __shfl_xor(colQ[nt], 16); colQ[nt] += __shfl_xor(colQ[nt], 32);
  }
  if (q == 0) {
#pragma unroll
    for (int nt = 0; nt < 2; ++nt) {
      int c = wn + nt * 16 + r16;
      atomicAdd(&sb[c], colS[nt]);
      atomicAdd(&sb[512 + c], colQ[nt]);
    }
  }
}

// ---- layer 1 fused (BM=40, grid 250): agg16 + MLP-A (VALU) -> At -> gemmB ----
__global__ __launch_bounds__(1024, 2) void k_l1m(const float* __restrict__ x,
    const int* __restrict__ rowptr, const int* __restrict__ col,
    const float* __restrict__ W1a, const float* __restrict__ b1a,
    const u16* __restrict__ WzB, const float* __restrict__ bB,
    u16* __restrict__ Hout, float* __restrict__ statsOut) {
  __shared__ float T0[BM][17];
  __shared__ __align__(16) u16 At[BMT * 576];   // 54 KB swizzled
  const int T = threadIdx.x;
  const int M0 = blockIdx.x * BM;
  // agg16: threads 0..639 = (node, ch), serial edge loop (same order as ref)
  if (T < BM * 16) {
    int nl = T >> 4, ch = T & 15;
    int node = M0 + nl;
    float acc = 0.f;
    if (node < NODES) {
      acc = x[(size_t)node * INF_ + ch];
      int r1 = rowptr[node + 1];
      for (int idx = rowptr[node]; idx < r1; ++idx)
        acc += x[(size_t)col[idx] * INF_ + ch];
    }
    T0[nl][ch] = acc;
  }
  __syncthreads();
  // MLP-A: thread = (col, row-half); 20 rows each; write relu fp16 into At
  {
    int c = T & 511;
    int h = T >> 9;                    // 0..1 -> rows [h*20, h*20+20)
    float wreg[16];
#pragma unroll
    for (int k = 0; k < 16; ++k) wreg[k] = W1a[k * DD + c];
    float bv = b1a[c];
    for (int r = h * 20; r < h * 20 + 20; ++r) {
      float s = bv;
#pragma unroll
      for (int k = 0; k < 16; ++k) s = fmaf(T0[r][k], wreg[k], s);
      At[lds_m(r, c * 2)] = f2h(fmaxf(s, 0.f));
    }
  }
  // zero pad rows 40..47 (8 rows x 64 x 16B) with threads 0..511
  if (T < 512) {
    int r = BM + (T >> 6);
    *(uint4*)(At + lds_m(r, (T & 63) * 16)) = make_uint4(0u, 0u, 0u, 0u);
  }
  __syncthreads();
  const int lane = T & 63, wave = T >> 6;
  const int q = lane >> 4, r16 = lane & 15;
  f32x4 acc[3][2] = {};
  gemm_tile(At, WzB, wave, q, r16, acc);
  gemm_out(acc, bB, Hout, statsOut + (size_t)(blockIdx.x & (NBUCK - 1)) * 1024,
           M0, wave, q, r16);
}

// ---- fused layer (BM=40, grid 250): BN-finalize -> gather+affine -> gemmA -> Mid -> gemmB ----
// One block per CU (250 of 256), single scheduling wave; Mid pad rows hold
// relu(bias) junk but only pollute output rows >= BM which are discarded.
__global__ __launch_bounds__(1024, 2) void k_fused(
    const u16* __restrict__ Hin, const int* __restrict__ rowptr, const int* __restrict__ col,
    const float* __restrict__ statsIn, const float* __restrict__ gamma, const float* __restrict__ beta,
    const u16* __restrict__ WzA, const float* __restrict__ bA,
    const u16* __restrict__ WzB, const float* __restrict__ bB,
    u16* __restrict__ Hout, float* __restrict__ statsOut) {
  __shared__ float ssc[512], ssh[512];
  __shared__ __align__(16) u16 At[BMT * 576];   // 54 KB swizzled; Mid reuses it
  const int T = threadIdx.x;
  const int M0 = blockIdx.x * BM;
  // phase 0: BN finalize from buckets (threads 0..511)
  if (T < 512) {
    int c = T;
    float s = 0.f, qv = 0.f;
#pragma unroll
    for (int b = 0; b < NBUCK; ++b) {
      s += statsIn[b * 1024 + c];
      qv += statsIn[b * 1024 + 512 + c];
    }
    float mean = s * (1.f / NODES);
    float var = qv * (1.f / NODES) - mean * mean;
    float sc = gamma[c] * rsqrtf(var + BN_EPS);
    ssc[c] = sc;
    ssh[c] = beta[c] - mean * sc;
  }
  __syncthreads();
  // phase 1: gather 40 nodes; waves 0..15 take nodes 2w,2w+1; waves 0..7 also
  // take node 32+w; waves 8..15 zero the pad rows 40..47.
  const int lane = T & 63, wave = T >> 6;
  const int c8 = lane * 8;
  const u16* hp = Hin + c8;
  float4 scA = *(const float4*)(ssc + c8), scB = *(const float4*)(ssc + c8 + 4);
  float4 shA = *(const float4*)(ssh + c8), shB = *(const float4*)(ssh + c8 + 4);
  for (int ps = 0; ps < 3; ++ps) {
    int nl;
    if (ps < 2) {
      nl = wave * 2 + ps;
    } else if (wave >= 8) {
      *(uint4*)(At + lds_m(BM + wave - 8, lane * 16)) = make_uint4(0u, 0u, 0u, 0u);
      continue;
    } else {
      nl = 32 + wave;
    }
    int node = M0 + nl;
    if (node < NODES) {
      float acc[8];
      {
        uint4 sv = *(const uint4*)(hp + (size_t)node * DD);
        acc[0] = h2f((u16)(sv.x & 0xffff)); acc[1] = h2f((u16)(sv.x >> 16));
        acc[2] = h2f((u16)(sv.y & 0xffff)); acc[3] = h2f((u16)(sv.y >> 16));
        acc[4] = h2f((u16)(sv.z & 0xffff)); acc[5] = h2f((u16)(sv.z >> 16));
        acc[6] = h2f((u16)(sv.w & 0xffff)); acc[7] = h2f((u16)(sv.w >> 16));
      }
      int r0 = rowptr[node], r1 = rowptr[node + 1];
      int idx = r0;
      for (; idx + 7 < r1; idx += 8) {
        int j0 = col[idx], j1 = col[idx + 1], j2 = col[idx + 2], j3 = col[idx + 3];
        int j4 = col[idx + 4], j5 = col[idx + 5], j6 = col[idx + 6], j7 = col[idx + 7];
        uint4 a = *(const uint4*)(hp + (size_t)j0 * DD);
        uint4 b = *(const uint4*)(hp + (size_t)j1 * DD);
        uint4 c = *(const uint4*)(hp + (size_t)j2 * DD);
        uint4 d = *(const uint4*)(hp + (size_t)j3 * DD);
        uint4 e = *(const uint4*)(hp + (size_t)j4 * DD);
        uint4 f = *(const uint4*)(hp + (size_t)j5 * DD);
        uint4 g = *(const uint4*)(hp + (size_t)j6 * DD);
        uint4 h = *(const uint4*)(hp + (size_t)j7 * DD);
        add8(a, acc); add8(b, acc); add8(c, acc); add8(d, acc);
        add8(e, acc); add8(f, acc); add8(g, acc); add8(h, acc);
      }
      for (; idx + 3 < r1; idx += 4) {
        int j0 = col[idx], j1 = col[idx + 1], j2 = col[idx + 2], j3 = col[idx + 3];
        uint4 a = *(const uint4*)(hp + (size_t)j0 * DD);
        uint4 b = *(const uint4*)(hp + (size_t)j1 * DD);
        uint4 c = *(const uint4*)(hp + (size_t)j2 * DD);
        uint4 d = *(const uint4*)(hp + (size_t)j3 * DD);
        add8(a, acc); add8(b, acc); add8(c, acc); add8(d, acc);
      }
      for (; idx < r1; ++idx) {
        uint4 a = *(const uint4*)(hp + (size_t)col[idx] * DD);
        add8(a, acc);
      }
      float nn = (float)(r1 - r0 + 1);
      uint4 o;
      o.x = pk(scA.x * acc[0] + nn * shA.x, scA.y * acc[1] + nn * shA.y);
      o.y = pk(scA.z * acc[2] + nn * shA.z, scA.w * acc[3] + nn * shA.w);
      o.z = pk(scB.x * acc[4] + nn * shB.x, scB.y * acc[5] + nn * shB.y);
      o.w = pk(scB.z * acc[6] + nn * shB.z, scB.w * acc[7] + nn * shB.w);
      *(uint4*)(At + lds_m(nl, lane * 16)) = o;
    } else {
      *(uint4*)(At + lds_m(nl, lane * 16)) = make_uint4(0u, 0u, 0u, 0u);
    }
  }
  __syncthreads();
  // phase 2: gemmA -> Mid (LDS, reuses At) -> gemmB -> Hout + stats
  const int q = lane >> 4, r16 = lane & 15;
  const int wn = wave * 32;
  {
    f32x4 acc[3][2] = {};
    gemm_tile(At, WzA, wave, q, r16, acc);
    __syncthreads();                 // all reads of At done
#pragma unroll
    for (int nt = 0; nt < 2; ++nt) {
      int c = wn + nt * 16 + r16;
      float bv = bA[c];
#pragma unroll
      for (int mt = 0; mt < 3; ++mt)
#pragma unroll
        for (int rr = 0; rr < 4; ++rr)
          At[lds_m(mt * 16 + q * 4 + rr, c * 2)] = f2h(fmaxf(acc[mt][nt][rr] + bv, 0.f));
    }
    __syncthreads();                 // Mid ready
  }
  f32x4 acc[3][2] = {};
  gemm_tile(At, WzB, wave, q, r16, acc);
  gemm_out(acc, bB, Hout, statsOut + (size_t)(blockIdx.x & (NBUCK - 1)) * 1024,
           M0, wave, q, r16);
}

// ---- pooled partial sums: grid (GRAPHS, 8 slices), per-block binary-search bounds ----
__global__ __launch_bounds__(128) void k_pool_part(const u16* __restrict__ h, const int* __restrict__ batch,
                                                   float* __restrict__ gsum) {
  int g = blockIdx.x;
  int s = blockIdx.y;
  int c4 = threadIdx.x * 4;
  int r0 = lower_bound_dev(batch, g);
  int r1 = lower_bound_dev(batch, g + 1);
  int cnt = r1 - r0;
  int len = (cnt + 7) >> 3;
  int rs = r0 + s * len;
  int re = min(rs + len, r1);
  if (rs >= re) return;
  float4 acc = make_float4(0.f, 0.f, 0.f, 0.f);
  for (int r = rs; r < re; ++r) {
    ushort4 v = *(const ushort4*)(h + (size_t)r * DD + c4);
    acc.x += h2f(v.x); acc.y += h2f(v.y); acc.z += h2f(v.z); acc.w += h2f(v.w);
  }
  atomicAdd(&gsum[g * DD + c4 + 0], acc.x);
  atomicAdd(&gsum[g * DD + c4 + 1], acc.y);
  atomicAdd(&gsum[g * DD + c4 + 2], acc.z);
  atomicAdd(&gsum[g * DD + c4 + 3], acc.w);
}

// ---- head: feats = tanh(bn(mean) @ Wfc + bfc); grid (GRAPHS, 8 col-slices), K split 4-way ----
__global__ __launch_bounds__(256) void k_headf(const float* __restrict__ gsum, const int* __restrict__ batch,
                                               const float* __restrict__ stats,
                                               const float* __restrict__ gamma, const float* __restrict__ beta,
                                               const float* __restrict__ Wfc, const float* __restrict__ bfc,
                                               float* __restrict__ feats) {
  __shared__ float pv[512];
  __shared__ float red[4][64];
  int g = blockIdx.x;
  int t = threadIdx.x;
  int r0 = lower_bound_dev(batch, g);
  int r1 = lower_bound_dev(batch, g + 1);
  float inv = 1.f / fmaxf((float)(r1 - r0), 1.f);
#pragma unroll
  for (int r = 0; r < 2; ++r) {
    int c = t + r * 256;
    float s = 0.f, qv = 0.f;
#pragma unroll
    for (int b = 0; b < NBUCK; ++b) {
      s += stats[b * 1024 + c];
      qv += stats[b * 1024 + 512 + c];
    }
    float mean = s * (1.f / NODES);
    float var = qv * (1.f / NODES) - mean * mean;
    float sc = gamma[c] * rsqrtf(var + BN_EPS);
    float sh = beta[c] - mean * sc;
    pv[c] = gsum[g * DD + c] * inv * sc + sh;
  }
  __syncthreads();
  int colc = blockIdx.y * 64 + (t & 63);
  int kc = t >> 6;                      // 0..3
  float p = 0.f;
  int k0 = kc * 128;
  for (int k = k0; k < k0 + 128; ++k)
    p = fmaf(pv[k], Wfc[k * DD + colc], p);
  red[kc][t & 63] = p;
  __syncthreads();
  if (t < 64) {
    int c = blockIdx.y * 64 + t;
    float v = red[0][t] + red[1][t] + red[2][t] + red[3][t] + bfc[c];
    feats[g * DD + c] = tanhf(v);
  }
}

// ---- logits: grid (GRAPHS, NOUT), 64-lane wave reduction ----
__global__ __launch_bounds__(64) void k_logits2(const float* __restrict__ feats, const float* __restrict__ Wlog,
                                                const float* __restrict__ blog, float* __restrict__ out) {
  int g = blockIdx.x, o = blockIdx.y;
  int lane = threadIdx.x;
  float p = 0.f;
  for (int k = lane; k < DD; k += 64)
    p = fmaf(feats[g * DD + k], Wlog[k * NOUT + o], p);
#pragma unroll
  for (int off = 32; off > 0; off >>= 1)
    p += __shfl_down(p, off);
  if (lane == 0) out[g * NOUT + o] = p + blog[o];
}

extern "C" void kernel_launch(void* const* d_in, const int* in_sizes, int n_in,
                              void* d_out, int out_size, void* d_ws, size_t ws_size,
                              hipStream_t stream) {
  const float* x = (const float*)d_in[0];
  const int* ei = (const int*)d_in[1];
  const int* batch = (const int*)d_in[2];
  const float* W1a = (const float*)d_in[3];
  const float* b1a = (const float*)d_in[4];
  const float* W1b = (const float*)d_in[5];
  const float* b1b = (const float*)d_in[6];
  const float* Wa = (const float*)d_in[7];
  const float* ba = (const float*)d_in[8];
  const float* Wb = (const float*)d_in[9];
  const float* bb = (const float*)d_in[10];
  const float* bng = (const float*)d_in[11];
  const float* bnb = (const float*)d_in[12];
  const float* Wfc = (const float*)d_in[13];
  const float* bfc = (const float*)d_in[14];
  const float* Wlog = (const float*)d_in[15];
  const float* blog = (const float*)d_in[16];
  float* out = (float*)d_out;

  const int* src = ei;
  const int* dstp = ei + EDGES;

  char* w = (char*)d_ws;
  int* rowptr  = (int*)(w);                 // 10001 i32 (pad to 40192)
  int* cur     = (int*)(w + 40192);         // 10000 i32
  int* col     = (int*)(w + 80384);         // 160000 i32 -> ends 720384
  float* bns   = (float*)(w + 720384);      // 5 x NBUCK x 1024 f -> ends 884224
  float* gsum  = (float*)(w + 884224);      // 32768 f (contiguous after bns) -> ends 1015296
  float* feats = (float*)(w + 1015296);     // 32768 f -> ends 1146368
  u16* Wf      = (u16*)(w + 1146368);       // 9 x 512 KB fragment-major -> ends 5864960
  u16* H0      = (u16*)(w + 5864960);       // 10,240,000 B
  u16* H1      = (u16*)(w + 16104960);      // 10,240,000 B -> ends 26,344,960

  k_prep<<<2632, 256, 0, stream>>>(cur, bns, W1b, Wa, Wb, Wf);
  k_count<<<625, 256, 0, stream>>>(dstp, cur);
  k_scan<<<1, 1024, 0, stream>>>(cur, rowptr);
  k_fill<<<625, 256, 0, stream>>>(src, dstp, rowptr, cur, col);

  // layer 1 (one kernel): agg16 + MLP-A + gemmB -> H0 + stats0
  k_l1m<<<250, 1024, 0, stream>>>(x, rowptr, col, W1a, b1a, Wf, b1b, H0, bns);

  // layers 2..5 (one kernel each): bnf + gather + double-gemm, ping-pong H0<->H1
  u16* Hin = H0;
  u16* Ho = H1;
  for (int i = 0; i < 4; ++i) {
    k_fused<<<250, 1024, 0, stream>>>(Hin, rowptr, col, bns + (size_t)i * 8192,
        bng + i * DD, bnb + i * DD,
        Wf + (size_t)(1 + i) * 262144, ba + i * DD,
        Wf + (size_t)(5 + i) * 262144, bb + i * DD,
        Ho, bns + (size_t)(i + 1) * 8192);
    u16* tmp = Hin; Hin = Ho; Ho = tmp;
  }

  k_pool_part<<<dim3(GRAPHS, 8), 128, 0, stream>>>(Hin, batch, gsum);
  k_headf<<<dim3(GRAPHS, 8), 256, 0, stream>>>(gsum, batch, bns + (size_t)4 * 8192,
                                               bng + 4 * DD, bnb + 4 * DD, Wfc, bfc, feats);
  k_logits2<<<dim3(GRAPHS, NOUT), 64, 0, stream>>>(feats, Wlog, blog, out);
}

// Round 10
// 349.616 us; speedup vs baseline: 1.2602x; 1.0016x over previous
//
#include <hip/hip_runtime.h>

#define NODES 10000
#define EDGES 160000
#define INF_ 16
#define DD 512
#define GRAPHS 64
#define NOUT 18
#define BN_EPS 1e-5f
#define NBUCK 8
#define BM 40            // rows per block; 250*40 = 10000 exact (one scheduling wave)
#define BMT 48           // padded LDS tile rows (3 x 16 MFMA tiles)

using u16 = unsigned short;
using u32 = unsigned int;
typedef __attribute__((ext_vector_type(8))) _Float16 f16x8;
typedef __attribute__((ext_vector_type(4))) float f32x4;

__device__ __forceinline__ float h2f(u16 u) {
  union { u16 u; _Float16 h; } v; v.u = u; return (float)v.h;
}
__device__ __forceinline__ u16 f2h(float f) {
  union { u16 u; _Float16 h; } v; v.h = (_Float16)f; return v.u;
}
__device__ __forceinline__ void add8(uint4 u, float* a) {
  a[0] += h2f((u16)(u.x & 0xffff)); a[1] += h2f((u16)(u.x >> 16));
  a[2] += h2f((u16)(u.y & 0xffff)); a[3] += h2f((u16)(u.y >> 16));
  a[4] += h2f((u16)(u.z & 0xffff)); a[5] += h2f((u16)(u.z >> 16));
  a[6] += h2f((u16)(u.w & 0xffff)); a[7] += h2f((u16)(u.w >> 16));
}
__device__ __forceinline__ unsigned int pk(float a, float b) {
  return (unsigned int)f2h(a) | ((unsigned int)f2h(b) << 16);
}
__device__ __forceinline__ int lower_bound_dev(const int* __restrict__ batch, int g) {
  int lo = 0, hi = NODES;
  while (lo < hi) { int m = (lo + hi) >> 1; if (batch[m] < g) lo = m + 1; else hi = m; }
  return lo;
}
// Swizzled LDS index (u16 units) for the 48-row A/Mid tile.
// Row stride 1152 B (== 0 mod 128) + XOR of byte-bits 4..6 with row&7.
__device__ __forceinline__ int lds_m(int row, int byte) {
  return (row * 1152 + (byte ^ ((row & 7) << 4))) >> 1;
}

// ---- prep: zero bns+gsum + cur, and transpose weights into FRAGMENT-MAJOR fp16 ----
// Wf layout per z-matrix (512 KB): [ntile(32)][kchunk(16)] blocks of 1 KB,
// block = [r16(16)][q(4)][e(8)] fp16 with element = W[kchunk*32+q*8+e][ntile*16+r16].
__global__ __launch_bounds__(256) void k_prep(int* __restrict__ cur, float* __restrict__ bg,
                                              const float* __restrict__ W1b, const float* __restrict__ Wa,
                                              const float* __restrict__ Wb, u16* __restrict__ Wf) {
  __shared__ float tile[32][33];
  int b = blockIdx.x;
  int t = threadIdx.x;
  if (b < 288) {               // zero bns+gsum: 5*NBUCK*1024 + 64*512 = 73728 floats
    bg[b * 256 + t] = 0.f;
    return;
  }
  if (b < 328) {               // zero cur: 10000 ints
    int i = (b - 288) * 256 + t;
    if (i < NODES) cur[i] = 0;
    return;
  }
  int wb = b - 328;            // 0..2303 : 16 nb x 16 kb x 9 z
  int nb = wb & 15, kb = (wb >> 4) & 15, z = wb >> 8;
  const float* src = (z == 0) ? W1b : (z <= 4 ? Wa + (size_t)(z - 1) * DD * DD
                                              : Wb + (size_t)(z - 5) * DD * DD);
  int tx = t & 31, ty = t >> 5;  // 32 x 8
#pragma unroll
  for (int i = 0; i < 4; ++i)
    tile[ty + 8 * i][tx] = src[(size_t)(kb * 32 + ty + 8 * i) * DD + nb * 32 + tx];
  __syncthreads();
  u16* dst = Wf + (size_t)z * 262144;
#pragma unroll
  for (int p = 0; p < 4; ++p) {
    int i = t + 256 * p;               // 0..1023 over the 32x32 tile
    int ntl = i >> 9;                  // 0..1 (two 16-wide n-tiles)
    int rem = i & 511;                 // [r16][q][e]
    int kl = ((rem >> 3) & 3) * 8 + (rem & 7);
    int nl = ntl * 16 + (rem >> 5);
    dst[(size_t)((nb * 2 + ntl) * 16 + kb) * 512 + rem] = f2h(tile[kl][nl]);
  }
}

// ---- CSR build: count -> scan(+reset) -> fill ----
__global__ void k_count(const int* __restrict__ dst, int* __restrict__ cnt) {
  int e = blockIdx.x * 256 + threadIdx.x;
  if (e < EDGES) atomicAdd(&cnt[dst[e]], 1);
}

__global__ __launch_bounds__(1024) void k_scan(int* __restrict__ cnt, int* __restrict__ rowptr) {
  __shared__ int s[1024];
  int t = threadIdx.x;
  int base = t * 10;
  int c[10]; int sum = 0;
#pragma unroll
  for (int i = 0; i < 10; ++i) {
    int idx = base + i;
    c[i] = (idx < NODES) ? cnt[idx] : 0;
    if (idx < NODES) cnt[idx] = 0;
    sum += c[i];
  }
  s[t] = sum; __syncthreads();
  for (int off = 1; off < 1024; off <<= 1) {
    int v = s[t];
    int a = (t >= off) ? s[t - off] : 0;
    __syncthreads();
    s[t] = v + a;
    __syncthreads();
  }
  int run = (t == 0) ? 0 : s[t - 1];
#pragma unroll
  for (int i = 0; i < 10; ++i) { int idx = base + i; if (idx < NODES) rowptr[idx] = run; run += c[i]; }
  if (t == 1023) rowptr[NODES] = s[1023];
}

__global__ void k_fill(const int* __restrict__ src, const int* __restrict__ dst,
                       const int* __restrict__ rowptr, int* __restrict__ cur, int* __restrict__ col) {
  int e = blockIdx.x * 256 + threadIdx.x;
  if (e < EDGES) {
    int d = dst[e];
    int p = atomicAdd(&cur[d], 1);
    col[rowptr[d] + p] = src[e];
  }
}

// ---- weight prefetch: first two ks-fragments for a wave's 32 columns ----
__device__ __forceinline__ void preloadW(const u16* __restrict__ wp, f16x8 (&p0)[2], f16x8 (&p1)[2]) {
#pragma unroll
  for (int nt = 0; nt < 2; ++nt) p0[nt] = *(const f16x8*)(wp + (size_t)(nt * 16) * 512);
#pragma unroll
  for (int nt = 0; nt < 2; ++nt) p1[nt] = *(const f16x8*)(wp + (size_t)(nt * 16 + 1) * 512);
}

// ---- pipelined 16x16x32 GEMM over the staged 48-row tile (per-wave 32 cols) ----
// 2-ahead weight pipeline: consume p0, shift p1->p0, issue ks+2. Exposed L2
// latency per ks-step drops from ~350cy (bh loaded at use, VGPR52 codegen) to ~0.
__device__ __forceinline__ void gemm_tile(const u16* At, const u16* __restrict__ wp,
                                          int q, int r16, f32x4 (&acc)[3][2],
                                          f16x8 (&p0)[2], f16x8 (&p1)[2]) {
#pragma unroll
  for (int ks = 0; ks < 16; ++ks) {
    f16x8 af[3];
#pragma unroll
    for (int mt = 0; mt < 3; ++mt)
      af[mt] = *(const f16x8*)(At + lds_m(mt * 16 + r16, ks * 64 + q * 16));
    f16x8 c0 = p0[0], c1 = p0[1];
    p0[0] = p1[0]; p0[1] = p1[1];
    if (ks < 14) {
#pragma unroll
      for (int nt = 0; nt < 2; ++nt)
        p1[nt] = *(const f16x8*)(wp + (size_t)(nt * 16 + ks + 2) * 512);
    }
#pragma unroll
    for (int mt = 0; mt < 3; ++mt) {
      acc[mt][0] = __builtin_amdgcn_mfma_f32_16x16x32_f16(af[mt], c0, acc[mt][0], 0, 0, 0);
      acc[mt][1] = __builtin_amdgcn_mfma_f32_16x16x32_f16(af[mt], c1, acc[mt][1], 0, 0, 0);
    }
  }
}

// ---- shared epilogue: bias + relu + fp16 store + bucketed BN stats (rows < BM only) ----
__device__ __forceinline__ void gemm_out(f32x4 (&acc)[3][2], const float* __restrict__ bB,
                                         u16* __restrict__ Hout, float* __restrict__ sb,
                                         int M0, int wave, int q, int r16) {
  const int wn = wave * 32;
  float colS[2] = {}, colQ[2] = {};
#pragma unroll
  for (int nt = 0; nt < 2; ++nt) {
    int c = wn + nt * 16 + r16;
    float bv = bB[c];
#pragma unroll
    for (int mt = 0; mt < 3; ++mt) {
#pragma unroll
      for (int rr = 0; rr < 4; ++rr) {
        int lr = mt * 16 + q * 4 + rr;
        int row = M0 + lr;
        if (lr < BM && row < NODES) {
          float v = fmaxf(acc[mt][nt][rr] + bv, 0.f);
          Hout[(size_t)row * DD + c] = f2h(v);
          colS[nt] += v; colQ[nt] += v * v;
        }
      }
    }
  }
#pragma unroll
  for (int nt = 0; nt < 2; ++nt) {
    colS[nt] += __shfl_xor(colS[nt], 16); colS[nt] += __shfl_xor(colS[nt], 32);
    colQ[nt] += __shfl_xor(colQ[nt], 16); colQ[nt] += __shfl_xor(colQ[nt], 32);
  }
  if (q == 0) {
#pragma unroll
    for (int nt = 0; nt < 2; ++nt) {
      int c = wn + nt * 16 + r16;
      atomicAdd(&sb[c], colS[nt]);
      atomicAdd(&sb[512 + c], colQ[nt]);
    }
  }
}

// ---- layer 1 fused (BM=40, grid 250): agg16 + MLP-A (VALU) -> At -> gemmB ----
__global__ __launch_bounds__(1024, 2) void k_l1m(const float* __restrict__ x,
    const int* __restrict__ rowptr, const int* __restrict__ col,
    const float* __restrict__ W1a, const float* __restrict__ b1a,
    const u16* __restrict__ WzB, const float* __restrict__ bB,
    u16* __restrict__ Hout, float* __restrict__ statsOut) {
  __shared__ float T0[BM][17];
  __shared__ __align__(16) u16 At[BMT * 576];   // 54 KB swizzled
  const int T = threadIdx.x;
  const int M0 = blockIdx.x * BM;
  const int lane = T & 63, wave = T >> 6;
  const int q = lane >> 4, r16 = lane & 15;
  // issue gemmB's first weight fragments NOW: they fly under agg16 + MLP-A
  const u16* wpB = WzB + (size_t)(wave * 2) * 16 * 512 + (r16 * 4 + q) * 8;
  f16x8 b0[2], b1[2];
  preloadW(wpB, b0, b1);
  // agg16: threads 0..639 = (node, ch), serial edge loop (same order as ref)
  if (T < BM * 16) {
    int nl = T >> 4, ch = T & 15;
    int node = M0 + nl;
    float acc = 0.f;
    if (node < NODES) {
      acc = x[(size_t)node * INF_ + ch];
      int r1 = rowptr[node + 1];
      for (int idx = rowptr[node]; idx < r1; ++idx)
        acc += x[(size_t)col[idx] * INF_ + ch];
    }
    T0[nl][ch] = acc;
  }
  __syncthreads();
  // MLP-A: thread = (col, row-half); 20 rows each; write relu fp16 into At
  {
    int c = T & 511;
    int h = T >> 9;                    // 0..1 -> rows [h*20, h*20+20)
    float wreg[16];
#pragma unroll
    for (int k = 0; k < 16; ++k) wreg[k] = W1a[k * DD + c];
    float bv = b1a[c];
    for (int r = h * 20; r < h * 20 + 20; ++r) {
      float s = bv;
#pragma unroll
      for (int k = 0; k < 16; ++k) s = fmaf(T0[r][k], wreg[k], s);
      At[lds_m(r, c * 2)] = f2h(fmaxf(s, 0.f));
    }
  }
  // zero pad rows 40..47 (8 rows x 64 x 16B) with threads 0..511
  if (T < 512) {
    int r = BM + (T >> 6);
    *(uint4*)(At + lds_m(r, (T & 63) * 16)) = make_uint4(0u, 0u, 0u, 0u);
  }
  __syncthreads();
  f32x4 acc[3][2] = {};
  gemm_tile(At, wpB, q, r16, acc, b0, b1);
  gemm_out(acc, bB, Hout, statsOut + (size_t)(blockIdx.x & (NBUCK - 1)) * 1024,
           M0, wave, q, r16);
}

// ---- fused layer (BM=40, grid 250): BN-finalize -> gather+affine -> gemmA -> Mid -> gemmB ----
// Weight pipeline: gemmA's first fragments issued at kernel entry (fly under
// bnf+gather); gemmB's issued before the Mid barriers; both gemms 2-ahead inside.
__global__ __launch_bounds__(1024, 2) void k_fused(
    const u16* __restrict__ Hin, const int* __restrict__ rowptr, const int* __restrict__ col,
    const float* __restrict__ statsIn, const float* __restrict__ gamma, const float* __restrict__ beta,
    const u16* __restrict__ WzA, const float* __restrict__ bA,
    const u16* __restrict__ WzB, const float* __restrict__ bB,
    u16* __restrict__ Hout, float* __restrict__ statsOut) {
  __shared__ float ssc[512], ssh[512];
  __shared__ __align__(16) u16 At[BMT * 576];   // 54 KB swizzled; Mid reuses it
  const int T = threadIdx.x;
  const int M0 = blockIdx.x * BM;
  const int lane = T & 63, wave = T >> 6;
  const int q = lane >> 4, r16 = lane & 15;
  const int woff = (size_t)(wave * 2) * 16 * 512 + (r16 * 4 + q) * 8;
  const u16* wpA = WzA + woff;
  const u16* wpB = WzB + woff;
  // issue gemmA's first weight fragments NOW: they fly under bnf + gather
  f16x8 a0[2], a1[2];
  preloadW(wpA, a0, a1);
  // phase 0: BN finalize from buckets (threads 0..511)
  if (T < 512) {
    int c = T;
    float s = 0.f, qv = 0.f;
#pragma unroll
    for (int b = 0; b < NBUCK; ++b) {
      s += statsIn[b * 1024 + c];
      qv += statsIn[b * 1024 + 512 + c];
    }
    float mean = s * (1.f / NODES);
    float var = qv * (1.f / NODES) - mean * mean;
    float sc = gamma[c] * rsqrtf(var + BN_EPS);
    ssc[c] = sc;
    ssh[c] = beta[c] - mean * sc;
  }
  __syncthreads();
  // phase 1: gather 40 nodes; waves 0..15 take nodes 2w,2w+1; waves 0..7 also
  // take node 32+w; waves 8..15 zero the pad rows 40..47.
  const int c8 = lane * 8;
  const u16* hp = Hin + c8;
  float4 scA = *(const float4*)(ssc + c8), scB = *(const float4*)(ssc + c8 + 4);
  float4 shA = *(const float4*)(ssh + c8), shB = *(const float4*)(ssh + c8 + 4);
  for (int ps = 0; ps < 3; ++ps) {
    int nl;
    if (ps < 2) {
      nl = wave * 2 + ps;
    } else if (wave >= 8) {
      *(uint4*)(At + lds_m(BM + wave - 8, lane * 16)) = make_uint4(0u, 0u, 0u, 0u);
      continue;
    } else {
      nl = 32 + wave;
    }
    int node = M0 + nl;
    if (node < NODES) {
      float acc[8];
      {
        uint4 sv = *(const uint4*)(hp + (size_t)node * DD);
        acc[0] = h2f((u16)(sv.x & 0xffff)); acc[1] = h2f((u16)(sv.x >> 16));
        acc[2] = h2f((u16)(sv.y & 0xffff)); acc[3] = h2f((u16)(sv.y >> 16));
        acc[4] = h2f((u16)(sv.z & 0xffff)); acc[5] = h2f((u16)(sv.z >> 16));
        acc[6] = h2f((u16)(sv.w & 0xffff)); acc[7] = h2f((u16)(sv.w >> 16));
      }
      int r0 = rowptr[node], r1 = rowptr[node + 1];
      int idx = r0;
      for (; idx + 7 < r1; idx += 8) {
        int j0 = col[idx], j1 = col[idx + 1], j2 = col[idx + 2], j3 = col[idx + 3];
        int j4 = col[idx + 4], j5 = col[idx + 5], j6 = col[idx + 6], j7 = col[idx + 7];
        uint4 a = *(const uint4*)(hp + (size_t)j0 * DD);
        uint4 b = *(const uint4*)(hp + (size_t)j1 * DD);
        uint4 c = *(const uint4*)(hp + (size_t)j2 * DD);
        uint4 d = *(const uint4*)(hp + (size_t)j3 * DD);
        uint4 e = *(const uint4*)(hp + (size_t)j4 * DD);
        uint4 f = *(const uint4*)(hp + (size_t)j5 * DD);
        uint4 g = *(const uint4*)(hp + (size_t)j6 * DD);
        uint4 h = *(const uint4*)(hp + (size_t)j7 * DD);
        add8(a, acc); add8(b, acc); add8(c, acc); add8(d, acc);
        add8(e, acc); add8(f, acc); add8(g, acc); add8(h, acc);
      }
      for (; idx + 3 < r1; idx += 4) {
        int j0 = col[idx], j1 = col[idx + 1], j2 = col[idx + 2], j3 = col[idx + 3];
        uint4 a = *(const uint4*)(hp + (size_t)j0 * DD);
        uint4 b = *(const uint4*)(hp + (size_t)j1 * DD);
        uint4 c = *(const uint4*)(hp + (size_t)j2 * DD);
        uint4 d = *(const uint4*)(hp + (size_t)j3 * DD);
        add8(a, acc); add8(b, acc); add8(c, acc); add8(d, acc);
      }
      for (; idx < r1; ++idx) {
        uint4 a = *(const uint4*)(hp + (size_t)col[idx] * DD);
        add8(a, acc);
      }
      float nn = (float)(r1 - r0 + 1);
      uint4 o;
      o.x = pk(scA.x * acc[0] + nn * shA.x, scA.y * acc[1] + nn * shA.y);
      o.y = pk(scA.z * acc[2] + nn * shA.z, scA.w * acc[3] + nn * shA.w);
      o.z = pk(scB.x * acc[4] + nn * shB.x, scB.y * acc[5] + nn * shB.y);
      o.w = pk(scB.z * acc[6] + nn * shB.z, scB.w * acc[7] + nn * shB.w);
      *(uint4*)(At + lds_m(nl, lane * 16)) = o;
    } else {
      *(uint4*)(At + lds_m(nl, lane * 16)) = make_uint4(0u, 0u, 0u, 0u);
    }
  }
  __syncthreads();
  // phase 2: gemmA -> Mid (LDS, reuses At) -> gemmB -> Hout + stats
  const int wn = wave * 32;
  f16x8 b0[2], b1[2];
  {
    f32x4 acc[3][2] = {};
    gemm_tile(At, wpA, q, r16, acc, a0, a1);
    preloadW(wpB, b0, b1);           // issue gemmB's first fragments: fly under barriers+Mid
    __syncthreads();                 // all reads of At done
#pragma unroll
    for (int nt = 0; nt < 2; ++nt) {
      int c = wn + nt * 16 + r16;
      float bv = bA[c];
#pragma unroll
      for (int mt = 0; mt < 3; ++mt)
#pragma unroll
        for (int rr = 0; rr < 4; ++rr)
          At[lds_m(mt * 16 + q * 4 + rr, c * 2)] = f2h(fmaxf(acc[mt][nt][rr] + bv, 0.f));
    }
    __syncthreads();                 // Mid ready
  }
  f32x4 acc[3][2] = {};
  gemm_tile(At, wpB, q, r16, acc, b0, b1);
  gemm_out(acc, bB, Hout, statsOut + (size_t)(blockIdx.x & (NBUCK - 1)) * 1024,
           M0, wave, q, r16);
}

// ---- pooled partial sums: grid (GRAPHS, 8 slices), per-block binary-search bounds ----
__global__ __launch_bounds__(128) void k_pool_part(const u16* __restrict__ h, const int* __restrict__ batch,
                                                   float* __restrict__ gsum) {
  int g = blockIdx.x;
  int s = blockIdx.y;
  int c4 = threadIdx.x * 4;
  int r0 = lower_bound_dev(batch, g);
  int r1 = lower_bound_dev(batch, g + 1);
  int cnt = r1 - r0;
  int len = (cnt + 7) >> 3;
  int rs = r0 + s * len;
  int re = min(rs + len, r1);
  if (rs >= re) return;
  float4 acc = make_float4(0.f, 0.f, 0.f, 0.f);
  for (int r = rs; r < re; ++r) {
    ushort4 v = *(const ushort4*)(h + (size_t)r * DD + c4);
    acc.x += h2f(v.x); acc.y += h2f(v.y); acc.z += h2f(v.z); acc.w += h2f(v.w);
  }
  atomicAdd(&gsum[g * DD + c4 + 0], acc.x);
  atomicAdd(&gsum[g * DD + c4 + 1], acc.y);
  atomicAdd(&gsum[g * DD + c4 + 2], acc.z);
  atomicAdd(&gsum[g * DD + c4 + 3], acc.w);
}

// ---- head: feats = tanh(bn(mean) @ Wfc + bfc); grid (GRAPHS, 8 col-slices), K split 4-way ----
__global__ __launch_bounds__(256) void k_headf(const float* __restrict__ gsum, const int* __restrict__ batch,
                                               const float* __restrict__ stats,
                                               const float* __restrict__ gamma, const float* __restrict__ beta,
                                               const float* __restrict__ Wfc, const float* __restrict__ bfc,
                                               float* __restrict__ feats) {
  __shared__ float pv[512];
  __shared__ float red[4][64];
  int g = blockIdx.x;
  int t = threadIdx.x;
  int r0 = lower_bound_dev(batch, g);
  int r1 = lower_bound_dev(batch, g + 1);
  float inv = 1.f / fmaxf((float)(r1 - r0), 1.f);
#pragma unroll
  for (int r = 0; r < 2; ++r) {
    int c = t + r * 256;
    float s = 0.f, qv = 0.f;
#pragma unroll
    for (int b = 0; b < NBUCK; ++b) {
      s += stats[b * 1024 + c];
      qv += stats[b * 1024 + 512 + c];
    }
    float mean = s * (1.f / NODES);
    float var = qv * (1.f / NODES) - mean * mean;
    float sc = gamma[c] * rsqrtf(var + BN_EPS);
    float sh = beta[c] - mean * sc;
    pv[c] = gsum[g * DD + c] * inv * sc + sh;
  }
  __syncthreads();
  int colc = blockIdx.y * 64 + (t & 63);
  int kc = t >> 6;                      // 0..3
  float p = 0.f;
  int k0 = kc * 128;
  for (int k = k0; k < k0 + 128; ++k)
    p = fmaf(pv[k], Wfc[k * DD + colc], p);
  red[kc][t & 63] = p;
  __syncthreads();
  if (t < 64) {
    int c = blockIdx.y * 64 + t;
    float v = red[0][t] + red[1][t] + red[2][t] + red[3][t] + bfc[c];
    feats[g * DD + c] = tanhf(v);
  }
}

// ---- logits: grid (GRAPHS, NOUT), 64-lane wave reduction ----
__global__ __launch_bounds__(64) void k_logits2(const float* __restrict__ feats, const float* __restrict__ Wlog,
                                                const float* __restrict__ blog, float* __restrict__ out) {
  int g = blockIdx.x, o = blockIdx.y;
  int lane = threadIdx.x;
  float p = 0.f;
  for (int k = lane; k < DD; k += 64)
    p = fmaf(feats[g * DD + k], Wlog[k * NOUT + o], p);
#pragma unroll
  for (int off = 32; off > 0; off >>= 1)
    p += __shfl_down(p, off);
  if (lane == 0) out[g * NOUT + o] = p + blog[o];
}

extern "C" void kernel_launch(void* const* d_in, const int* in_sizes, int n_in,
                              void* d_out, int out_size, void* d_ws, size_t ws_size,
                              hipStream_t stream) {
  const float* x = (const float*)d_in[0];
  const int* ei = (const int*)d_in[1];
  const int* batch = (const int*)d_in[2];
  const float* W1a = (const float*)d_in[3];
  const float* b1a = (const float*)d_in[4];
  const float* W1b = (const float*)d_in[5];
  const float* b1b = (const float*)d_in[6];
  const float* Wa = (const float*)d_in[7];
  const float* ba = (const float*)d_in[8];
  const float* Wb = (const float*)d_in[9];
  const float* bb = (const float*)d_in[10];
  const float* bng = (const float*)d_in[11];
  const float* bnb = (const float*)d_in[12];
  const float* Wfc = (const float*)d_in[13];
  const float* bfc = (const float*)d_in[14];
  const float* Wlog = (const float*)d_in[15];
  const float* blog = (const float*)d_in[16];
  float* out = (float*)d_out;

  const int* src = ei;
  const int* dstp = ei + EDGES;

  char* w = (char*)d_ws;
  int* rowptr  = (int*)(w);                 // 10001 i32 (pad to 40192)
  int* cur     = (int*)(w + 40192);         // 10000 i32
  int* col     = (int*)(w + 80384);         // 160000 i32 -> ends 720384
  float* bns   = (float*)(w + 720384);      // 5 x NBUCK x 1024 f -> ends 884224
  float* gsum  = (float*)(w + 884224);      // 32768 f (contiguous after bns) -> ends 1015296
  float* feats = (float*)(w + 1015296);     // 32768 f -> ends 1146368
  u16* Wf      = (u16*)(w + 1146368);       // 9 x 512 KB fragment-major -> ends 5864960
  u16* H0      = (u16*)(w + 5864960);       // 10,240,000 B
  u16* H1      = (u16*)(w + 16104960);      // 10,240,000 B -> ends 26,344,960

  k_prep<<<2632, 256, 0, stream>>>(cur, bns, W1b, Wa, Wb, Wf);
  k_count<<<625, 256, 0, stream>>>(dstp, cur);
  k_scan<<<1, 1024, 0, stream>>>(cur, rowptr);
  k_fill<<<625, 256, 0, stream>>>(src, dstp, rowptr, cur, col);

  // layer 1 (one kernel): agg16 + MLP-A + gemmB -> H0 + stats0
  k_l1m<<<250, 1024, 0, stream>>>(x, rowptr, col, W1a, b1a, Wf, b1b, H0, bns);

  // layers 2..5 (one kernel each): bnf + gather + double-gemm, ping-pong H0<->H1
  u16* Hin = H0;
  u16* Ho = H1;
  for (int i = 0; i < 4; ++i) {
    k_fused<<<250, 1024, 0, stream>>>(Hin, rowptr, col, bns + (size_t)i * 8192,
        bng + i * DD, bnb + i * DD,
        Wf + (size_t)(1 + i) * 262144, ba + i * DD,
        Wf + (size_t)(5 + i) * 262144, bb + i * DD,
        Ho, bns + (size_t)(i + 1) * 8192);
    u16* tmp = Hin; Hin = Ho; Ho = tmp;
  }

  k_pool_part<<<dim3(GRAPHS, 8), 128, 0, stream>>>(Hin, batch, gsum);
  k_headf<<<dim3(GRAPHS, 8), 256, 0, stream>>>(gsum, batch, bns + (size_t)4 * 8192,
                                               bng + 4 * DD, bnb + 4 * DD, Wfc, bfc, feats);
  k_logits2<<<dim3(GRAPHS, NOUT), 64, 0, stream>>>(feats, Wlog, blog, out);
}